// Round 9
// baseline (500.093 us; speedup 1.0000x reference)
//
#include <hip/hip_runtime.h>
#include <hip/hip_fp16.h>
#include <math.h>

// GAT 2-layer, N=100K nodes, E=1.6M edges (+N self loops), fp32 compute,
// fp16 feature rows (packed v_pk_fma_f16 aggregation).
// CSR build via 2-level bucket sort (bucket = dst>>7), ATOMIC-FREE at global
// scope: binA counts per (chunk,bucket) -> binB scans (bucket bases + per-chunk
// running bases) -> binC scatters with LDS-only cursors -> binD finalizes.
// Per-edge weights precomputed edge-parallel (k_w) into packed (w,src);
// agg loop: 4 uint2 weight loads + 4 row gathers + 16 hfma2 per 32 edges.

constexpr int F_IN = 128;
constexpr int F_H  = 64;
constexpr int F_O  = 40;
constexpr int BSH  = 7;                  // bucket shift
constexpr int BNODES = 1 << BSH;         // 128 nodes per bucket
constexpr int NBMAX = 1024;              // max buckets (N <= 131072)
constexpr int CHUNK = 4096;              // edges per block in binA/binC

__device__ __forceinline__ unsigned short f2h(float f) {
    return __half_as_ushort(__float2half(f));
}
union H2U { unsigned u; __half2 h; };
__device__ __forceinline__ __half2 u2h(unsigned u) { H2U t; t.u = u; return t.h; }
__device__ __forceinline__ unsigned h2u(__half2 h) { H2U t; t.h = h; return t.u; }

// ---------------- CSR build: bucket sort (no global atomics) ----------------

// Count: per-chunk LDS histogram -> contiguous row cnts[blk][bucket].
__global__ __launch_bounds__(256) void k_binA(const int* __restrict__ dsts,
                                              int* __restrict__ cnts,
                                              int E, int Et, int NB) {
    __shared__ int hist[NBMAX];
    int t = threadIdx.x;
    for (int i = t; i < NB; i += 256) hist[i] = 0;
    __syncthreads();
    int e0 = blockIdx.x * CHUNK;
#pragma unroll 4
    for (int it = 0; it < CHUNK / 256; ++it) {
        int e = e0 + it * 256 + t;
        if (e < Et) {
            int d = (e < E) ? dsts[e] : (e - E);
            atomicAdd(&hist[d >> BSH], 1);
        }
    }
    __syncthreads();
    int* row = cnts + (size_t)blockIdx.x * NB;
    for (int i = t; i < NB; i += 256) row[i] = hist[i];
}

// Scan: bucket totals (column sums) -> exclusive scan -> bbase/bend and
// per-(chunk,bucket) running base gbase[blk][bucket]. One block, 1024 thr.
__global__ __launch_bounds__(1024) void k_binB(const int* __restrict__ cnts,
                                               int* __restrict__ gbase,
                                               int* __restrict__ bbase,
                                               int* __restrict__ bend,
                                               int* __restrict__ rp,
                                               int NB, int N, int Et, int nblk) {
    __shared__ int lds[1024];
    int t = threadIdx.x;                 // bucket id
    int tot = 0;
    if (t < NB)
        for (int k = 0; k < nblk; ++k) tot += cnts[(size_t)k * NB + t];
    lds[t] = tot; __syncthreads();
    int x = tot;
    for (int o = 1; o < 1024; o <<= 1) {
        int y = (t >= o) ? lds[t - o] : 0;
        __syncthreads();
        x += y;
        lds[t] = x;
        __syncthreads();
    }
    int base = x - tot;                  // exclusive prefix
    if (t < NB) {
        bbase[t] = base;
        bend[t] = base + tot;
        int run = base;
        for (int k = 0; k < nblk; ++k) {
            gbase[(size_t)k * NB + t] = run;
            run += cnts[(size_t)k * NB + t];
        }
    }
    if (t == 0) rp[N] = Et;
}

// Scatter: absolute positions from gbase, LDS-only cursors.
__global__ __launch_bounds__(256) void k_binC(const int* __restrict__ srcs,
                                              const int* __restrict__ dsts,
                                              const int* __restrict__ gbase,
                                              unsigned* __restrict__ binned,
                                              int E, int Et, int NB) {
    __shared__ int lcnt[NBMAX];
    int t = threadIdx.x;
    const int* row = gbase + (size_t)blockIdx.x * NB;
    for (int i = t; i < NB; i += 256) lcnt[i] = row[i];
    __syncthreads();
    int e0 = blockIdx.x * CHUNK;
#pragma unroll 4
    for (int it = 0; it < CHUNK / 256; ++it) {
        int e = e0 + it * 256 + t;
        if (e < Et) {
            int s, d;
            if (e < E) { s = srcs[e]; d = dsts[e]; } else { s = e - E; d = s; }
            int b = d >> BSH;
            int p = atomicAdd(&lcnt[b], 1);
            binned[p] = (unsigned)s | ((unsigned)(d & (BNODES - 1)) << 24);
        }
    }
}

// Per-bucket finalize: node-level histogram + scan -> rp[] and final CSR.
__global__ __launch_bounds__(256) void k_binD(const unsigned* __restrict__ binned,
                                              const int* __restrict__ bbase,
                                              const int* __restrict__ bend,
                                              int* __restrict__ rp,
                                              int* __restrict__ csr, int N) {
    __shared__ int hist[BNODES];
    __shared__ int sc[256];
    __shared__ int lcnt[BNODES];
    int b = blockIdx.x, t = threadIdx.x;
    int base = bbase[b], end = bend[b];
    if (t < BNODES) hist[t] = 0;
    __syncthreads();
    for (int j = base + t; j < end; j += 256)
        atomicAdd(&hist[binned[j] >> 24], 1);
    __syncthreads();
    int v = (t < BNODES) ? hist[t] : 0;
    sc[t] = v; __syncthreads();
    int x = v;
    for (int o = 1; o < BNODES; o <<= 1) {
        int y = (t >= o) ? sc[t - o] : 0;
        __syncthreads();
        x += y;
        sc[t] = x;
        __syncthreads();
    }
    int pref = x - v;
    int g = (b << BSH) + t;
    if (t < BNODES && g < N) rp[g] = base + pref;
    if (t < BNODES) { sc[t] = pref; lcnt[t] = 0; }
    __syncthreads();
    for (int j = base + t; j < end; j += 256) {
        unsigned w = binned[j];
        int v2 = (int)(w >> 24);
        int s = (int)(w & 0xFFFFFFu);
        int p = atomicAdd(&lcnt[v2], 1);
        csr[base + sc[v2] + p] = s;
    }
}

// ---------------- GEMM1: h1 = fp16(x @ W1), fused fp32 alphas ----------------

__global__ __launch_bounds__(256) void k_gemm1(const float* __restrict__ x,
                                               const float* __restrict__ W,
                                               const float* __restrict__ avs,
                                               const float* __restrict__ avd,
                                               unsigned short* __restrict__ h,
                                               float* __restrict__ as,
                                               float* __restrict__ ad, int N) {
    __shared__ __align__(16) float Ws[F_IN * F_H];
    for (int i = threadIdx.x; i < F_IN * F_H; i += 256) Ws[i] = W[i];
    __syncthreads();
    int t = threadIdx.x;
    int r0 = blockIdx.x * 64 + (t >> 4) * 4;
    int c0 = (t & 15) * 4;
    if (r0 >= N) return;
    const float* xp = x + (size_t)r0 * F_IN;
    float acc[4][4] = {};
    for (int k4 = 0; k4 < F_IN / 4; ++k4) {
        int kb = k4 * 4;
        float4 w0 = *(const float4*)&Ws[(kb + 0) * F_H + c0];
        float4 w1 = *(const float4*)&Ws[(kb + 1) * F_H + c0];
        float4 w2 = *(const float4*)&Ws[(kb + 2) * F_H + c0];
        float4 w3 = *(const float4*)&Ws[(kb + 3) * F_H + c0];
#pragma unroll
        for (int r = 0; r < 4; ++r) {
            float4 xv = *(const float4*)&xp[(size_t)r * F_IN + kb];
            acc[r][0] += xv.x * w0.x + xv.y * w1.x + xv.z * w2.x + xv.w * w3.x;
            acc[r][1] += xv.x * w0.y + xv.y * w1.y + xv.z * w2.y + xv.w * w3.y;
            acc[r][2] += xv.x * w0.z + xv.y * w1.z + xv.z * w2.z + xv.w * w3.z;
            acc[r][3] += xv.x * w0.w + xv.y * w1.w + xv.z * w2.w + xv.w * w3.w;
        }
    }
    float4 avs4 = *(const float4*)&avs[c0];
    float4 avd4 = *(const float4*)&avd[c0];
#pragma unroll
    for (int r = 0; r < 4; ++r) {
        unsigned lo = (unsigned)f2h(acc[r][0]) | ((unsigned)f2h(acc[r][1]) << 16);
        unsigned hi = (unsigned)f2h(acc[r][2]) | ((unsigned)f2h(acc[r][3]) << 16);
        ((uint2*)h)[((size_t)(r0 + r) * F_H + c0) >> 2] = make_uint2(lo, hi);
        float ps = acc[r][0] * avs4.x + acc[r][1] * avs4.y + acc[r][2] * avs4.z + acc[r][3] * avs4.w;
        float pd = acc[r][0] * avd4.x + acc[r][1] * avd4.y + acc[r][2] * avd4.z + acc[r][3] * avd4.w;
#pragma unroll
        for (int o = 8; o; o >>= 1) {
            ps += __shfl_xor(ps, o, 16);
            pd += __shfl_xor(pd, o, 16);
        }
        if ((t & 15) == 0) { as[r0 + r] = ps; ad[r0 + r] = pd; }
    }
}

// ---------------- GEMM2: h2 = fp16(out1 @ W2) padded to 64 cols ----------------

__global__ __launch_bounds__(256) void k_gemm2(const float* __restrict__ xin,
                                               const float* __restrict__ W,
                                               const float* __restrict__ avs,
                                               const float* __restrict__ avd,
                                               unsigned short* __restrict__ h,
                                               float* __restrict__ as,
                                               float* __restrict__ ad, int N) {
    __shared__ __align__(16) float Ws[F_H * F_O];
    for (int i = threadIdx.x; i < F_H * F_O; i += 256) Ws[i] = W[i];
    __syncthreads();
    int t = threadIdx.x;
    int r0 = blockIdx.x * 64 + (t >> 3) * 2;
    int l = t & 7;
    if (r0 >= N) return;
    const float4* xa = (const float4*)(xin + (size_t)r0 * F_H);
    const float4* xb = (const float4*)(xin + (size_t)(r0 + 1) * F_H);
    float acca[5] = {}, accb[5] = {};
#pragma unroll
    for (int k4 = 0; k4 < F_H / 4; ++k4) {
        float4 xva = xa[k4];
        float4 xvb = xb[k4];
        int kb = k4 * 4;
#pragma unroll
        for (int kk = 0; kk < 4; ++kk) {
            const float* wr = &Ws[(kb + kk) * F_O + l];
            float w0 = wr[0], w1 = wr[8], w2 = wr[16], w3 = wr[24], w4 = wr[32];
            float xs = (&xva.x)[kk];
            acca[0] += xs * w0; acca[1] += xs * w1; acca[2] += xs * w2;
            acca[3] += xs * w3; acca[4] += xs * w4;
            float ys = (&xvb.x)[kk];
            accb[0] += ys * w0; accb[1] += ys * w1; accb[2] += ys * w2;
            accb[3] += ys * w3; accb[4] += ys * w4;
        }
    }
    float psa = 0.f, pda = 0.f, psb = 0.f, pdb = 0.f;
    unsigned short* ra = h + (size_t)r0 * F_H;     // padded row stride 64
    unsigned short* rb = h + (size_t)(r0 + 1) * F_H;
#pragma unroll
    for (int cc = 0; cc < 5; ++cc) {
        int c = l + 8 * cc;
        ra[c] = f2h(acca[cc]);
        rb[c] = f2h(accb[cc]);
        float vs = avs[c], vd = avd[c];
        psa += acca[cc] * vs; pda += acca[cc] * vd;
        psb += accb[cc] * vs; pdb += accb[cc] * vd;
    }
#pragma unroll
    for (int pp = 0; pp < 3; ++pp) {               // zero pad cols 40..63
        int c = 40 + l * 3 + pp;
        ra[c] = 0; rb[c] = 0;
    }
#pragma unroll
    for (int o = 4; o; o >>= 1) {
        psa += __shfl_xor(psa, o, 8);
        pda += __shfl_xor(pda, o, 8);
        psb += __shfl_xor(psb, o, 8);
        pdb += __shfl_xor(pdb, o, 8);
    }
    if (l == 0) { as[r0] = psa; ad[r0] = pda; as[r0 + 1] = psb; ad[r0 + 1] = pdb; }
}

// ---------------- Edge weights: w = exp(leaky(as[src]+ad[dst]) - 6) ----------

__global__ __launch_bounds__(256) void k_w(const int* __restrict__ rp,
                                           const int* __restrict__ csr,
                                           const float* __restrict__ as,
                                           const float* __restrict__ ad,
                                           uint2* __restrict__ ws, int N) {
    int i = (blockIdx.x * 256 + threadIdx.x) >> 6;
    if (i >= N) return;
    int lane = threadIdx.x & 63;
    int start = rp[i], end = rp[i + 1];
    float adi = ad[i];
    for (int j = start + lane; j < end; j += 64) {
        int s = csr[j];
        float e = as[s] + adi;
        e = (e > 0.f) ? e : 0.2f * e;
        ws[j] = make_uint2(__float_as_uint(__expf(e - 6.f)), (unsigned)s);
    }
}

// ---------------- Aggregation: one wave per dst node ----------------

template <int FOUT, bool RELU, bool LOGSM>
__global__ __launch_bounds__(256) void k_agg(const int* __restrict__ rp,
                                             const uint2* __restrict__ ws,
                                             const uint4* __restrict__ h4,
                                             const float* __restrict__ bias,
                                             float* __restrict__ out, int N) {
    int lane = threadIdx.x & 63;
    int i = (blockIdx.x * 256 + threadIdx.x) >> 6;
    if (i >= N) return;
    int start = rp[i], end = rp[i + 1];
    int grp = lane >> 3, c = lane & 7;
    int e1 = end - 1;
    __half2 a0[4] = {}, a1[4] = {};
    float sacc = 0.f;

    for (int jb = start; jb < end; jb += 32) {
        int j0 = jb + grp, j1 = jb + 8 + grp, j2 = jb + 16 + grp, j3 = jb + 24 + grp;
        uint2 t0 = ws[min(j0, e1)];
        uint2 t1 = ws[min(j1, e1)];
        uint2 t2 = ws[min(j2, e1)];
        uint2 t3 = ws[min(j3, e1)];
        uint4 h0 = h4[(size_t)t0.y * 8 + c];
        uint4 h1 = h4[(size_t)t1.y * 8 + c];
        uint4 h2 = h4[(size_t)t2.y * 8 + c];
        uint4 h3 = h4[(size_t)t3.y * 8 + c];
        float w0 = (j0 <= e1) ? __uint_as_float(t0.x) : 0.f;
        float w1 = (j1 <= e1) ? __uint_as_float(t1.x) : 0.f;
        float w2 = (j2 <= e1) ? __uint_as_float(t2.x) : 0.f;
        float w3 = (j3 <= e1) ? __uint_as_float(t3.x) : 0.f;
        sacc += (w0 + w1) + (w2 + w3);
        __half2 wh0 = __float2half2_rn(w0);
        __half2 wh1 = __float2half2_rn(w1);
        __half2 wh2 = __float2half2_rn(w2);
        __half2 wh3 = __float2half2_rn(w3);
        a0[0] = __hfma2(wh0, u2h(h0.x), a0[0]);
        a0[1] = __hfma2(wh0, u2h(h0.y), a0[1]);
        a0[2] = __hfma2(wh0, u2h(h0.z), a0[2]);
        a0[3] = __hfma2(wh0, u2h(h0.w), a0[3]);
        a1[0] = __hfma2(wh1, u2h(h1.x), a1[0]);
        a1[1] = __hfma2(wh1, u2h(h1.y), a1[1]);
        a1[2] = __hfma2(wh1, u2h(h1.z), a1[2]);
        a1[3] = __hfma2(wh1, u2h(h1.w), a1[3]);
        a0[0] = __hfma2(wh2, u2h(h2.x), a0[0]);
        a0[1] = __hfma2(wh2, u2h(h2.y), a0[1]);
        a0[2] = __hfma2(wh2, u2h(h2.z), a0[2]);
        a0[3] = __hfma2(wh2, u2h(h2.w), a0[3]);
        a1[0] = __hfma2(wh3, u2h(h3.x), a1[0]);
        a1[1] = __hfma2(wh3, u2h(h3.y), a1[1]);
        a1[2] = __hfma2(wh3, u2h(h3.z), a1[2]);
        a1[3] = __hfma2(wh3, u2h(h3.w), a1[3]);
    }
#pragma unroll
    for (int k = 0; k < 4; ++k) a0[k] = __hadd2(a0[k], a1[k]);
#pragma unroll
    for (int o = 8; o <= 32; o <<= 1) {
#pragma unroll
        for (int k = 0; k < 4; ++k) {
            unsigned u = __shfl_xor((int)h2u(a0[k]), o);
            a0[k] = __hadd2(a0[k], u2h((unsigned)u));
        }
        sacc += __shfl_xor(sacc, o);
    }
    float inv = 1.f / sacc;
    float f[8];
#pragma unroll
    for (int k = 0; k < 4; ++k) {
        float2 p = __half22float2(a0[k]);
        f[2 * k] = p.x; f[2 * k + 1] = p.y;
    }

    if (!LOGSM) {
        if (lane < 8) {
            float r[8];
#pragma unroll
            for (int k = 0; k < 8; ++k) {
                r[k] = f[k] * inv + bias[8 * lane + k];
                if (RELU) r[k] = fmaxf(r[k], 0.f);
            }
            float4* op = (float4*)(out + (size_t)i * FOUT + 8 * lane);
            op[0] = make_float4(r[0], r[1], r[2], r[3]);
            op[1] = make_float4(r[4], r[5], r[6], r[7]);
        }
    } else {
        constexpr int VC = FOUT / 8;         // valid chunks (5 for FOUT=40)
        bool act = (lane < VC);
        float v[8];
#pragma unroll
        for (int k = 0; k < 8; ++k)
            v[k] = act ? (f[k] * inv + bias[8 * lane + k]) : -INFINITY;
        float mx = v[0];
#pragma unroll
        for (int k = 1; k < 8; ++k) mx = fmaxf(mx, v[k]);
#pragma unroll
        for (int o = 1; o <= 4; o <<= 1) mx = fmaxf(mx, __shfl_xor(mx, o));
        float es = 0.f;
        if (act) {
#pragma unroll
            for (int k = 0; k < 8; ++k) es += __expf(v[k] - mx);
        }
#pragma unroll
        for (int o = 1; o <= 4; o <<= 1) es += __shfl_xor(es, o);
        if (act) {
            float lse = mx + __logf(es);
            float4* op = (float4*)(out + (size_t)i * FOUT + 8 * lane);
            op[0] = make_float4(v[0] - lse, v[1] - lse, v[2] - lse, v[3] - lse);
            op[1] = make_float4(v[4] - lse, v[5] - lse, v[6] - lse, v[7] - lse);
        }
    }
}

// ---------------- launch ----------------

extern "C" void kernel_launch(void* const* d_in, const int* in_sizes, int n_in,
                              void* d_out, int out_size, void* d_ws, size_t ws_size,
                              hipStream_t stream) {
    const float* x   = (const float*)d_in[0];
    const int* edges = (const int*)d_in[1];
    const float* W1  = (const float*)d_in[2];
    const float* av_s1 = (const float*)d_in[3];
    const float* av_d1 = (const float*)d_in[4];
    const float* b1  = (const float*)d_in[5];
    const float* W2  = (const float*)d_in[6];
    const float* av_s2 = (const float*)d_in[7];
    const float* av_d2 = (const float*)d_in[8];
    const float* b2  = (const float*)d_in[9];
    float* out = (float*)d_out;

    const int N  = in_sizes[0] / F_IN;
    const int E  = in_sizes[1] / 2;
    const int Et = E + N;
    const int NB = (N + BNODES - 1) >> BSH;
    const int nblkC = (Et + CHUNK - 1) / CHUNK;

    char* p = (char*)d_ws;
    auto alloc = [&](size_t bytes) {
        char* q = p;
        p += (bytes + 255) & ~(size_t)255;
        return (void*)q;
    };
    unsigned short* h1 = (unsigned short*)alloc((size_t)N * F_H * 2);  // fp16; reused as h2 (padded 64)
    float* out1   = (float*)alloc((size_t)N * F_H * 4);
    float* as1    = (float*)alloc((size_t)N * 4);
    float* ad1    = (float*)alloc((size_t)N * 4);
    float* as2    = (float*)alloc((size_t)N * 4);
    float* ad2    = (float*)alloc((size_t)N * 4);
    int* rp       = (int*)alloc((size_t)(N + 1) * 4);
    int* cnts     = (int*)alloc((size_t)nblkC * NBMAX * 4);
    int* gbase    = (int*)alloc((size_t)nblkC * NBMAX * 4);
    int* bbase    = (int*)alloc(NBMAX * 4);
    int* bend     = (int*)alloc(NBMAX * 4);
    unsigned* binned = (unsigned*)alloc((size_t)Et * 4);
    int* csr      = (int*)alloc((size_t)Et * 4);
    uint2* ws     = (uint2*)alloc((size_t)Et * 8);
    (void)n_in; (void)out_size; (void)ws_size;

    const int* srcs = edges;
    const int* dsts = edges + E;

    k_binA<<<nblkC, 256, 0, stream>>>(dsts, cnts, E, Et, NB);
    k_binB<<<1, 1024, 0, stream>>>(cnts, gbase, bbase, bend, rp, NB, N, Et, nblkC);
    k_binC<<<nblkC, 256, 0, stream>>>(srcs, dsts, gbase, binned, E, Et, NB);
    k_binD<<<NB, 256, 0, stream>>>(binned, bbase, bend, rp, csr, N);

    int gAgg = (N + 3) / 4;
    k_gemm1<<<(N + 63) / 64, 256, 0, stream>>>(x, W1, av_s1, av_d1, h1, as1, ad1, N);
    k_w<<<gAgg, 256, 0, stream>>>(rp, csr, as1, ad1, ws, N);
    k_agg<F_H, true, false><<<gAgg, 256, 0, stream>>>(rp, ws, (const uint4*)h1, b1, out1, N);
    k_gemm2<<<(N + 63) / 64, 256, 0, stream>>>(out1, W2, av_s2, av_d2, h1, as2, ad2, N);
    k_w<<<gAgg, 256, 0, stream>>>(rp, csr, as2, ad2, ws, N);
    k_agg<F_O, false, true><<<gAgg, 256, 0, stream>>>(rp, ws, (const uint4*)h1, b2, out, N);
}

// Round 10
// 342.311 us; speedup vs baseline: 1.4609x; 1.4609x over previous
//
#include <hip/hip_runtime.h>
#include <hip/hip_fp16.h>
#include <math.h>

// GAT 2-layer, N=100K nodes, E=1.6M edges (+N self loops), fp32 compute,
// fp16 feature rows (packed v_pk_fma_f16 aggregation).
// CSR build via 2-level bucket sort (bucket = dst>>7), no global atomics:
//   binA: per-chunk LDS histogram -> cntsT[bucket][chunk] (transposed)
//   binB1: wave/bucket coalesced sum -> btot
//   binB2: single-block scan of btot -> bbase/bend, rp[N]
//   binB3: block/bucket LDS scan of cntsT row + bbase -> gbaseT[bucket][chunk]
//   binC: scatter with LDS-only cursors seeded from gbaseT
//   binD: per-bucket node histogram+scan -> rp, final CSR
// Per-edge weights precomputed edge-parallel (k_w) into packed (w,src);
// agg loop: 4 uint2 weight loads + 4 row gathers + 16 hfma2 per 32 edges.

constexpr int F_IN = 128;
constexpr int F_H  = 64;
constexpr int F_O  = 40;
constexpr int BSH  = 7;                  // bucket shift
constexpr int BNODES = 1 << BSH;         // 128 nodes per bucket
constexpr int NBMAX = 1024;              // max buckets (N <= 131072)
constexpr int CHUNK = 8192;              // edges per chunk (binA/binC)

__device__ __forceinline__ unsigned short f2h(float f) {
    return __half_as_ushort(__float2half(f));
}
union H2U { unsigned u; __half2 h; };
__device__ __forceinline__ __half2 u2h(unsigned u) { H2U t; t.u = u; return t.h; }
__device__ __forceinline__ unsigned h2u(__half2 h) { H2U t; t.h = h; return t.u; }

// ---------------- CSR build ----------------

__global__ __launch_bounds__(256) void k_binA(const int* __restrict__ dsts,
                                              int* __restrict__ cntsT,
                                              int E, int Et, int NB, int nblk) {
    __shared__ int hist[NBMAX];
    int t = threadIdx.x;
    for (int i = t; i < NB; i += 256) hist[i] = 0;
    __syncthreads();
    int e0 = blockIdx.x * CHUNK;
#pragma unroll 4
    for (int it = 0; it < CHUNK / 256; ++it) {
        int e = e0 + it * 256 + t;
        if (e < Et) {
            int d = (e < E) ? dsts[e] : (e - E);
            atomicAdd(&hist[d >> BSH], 1);
        }
    }
    __syncthreads();
    for (int i = t; i < NB; i += 256)
        cntsT[(size_t)i * nblk + blockIdx.x] = hist[i];
}

// One wave per bucket: coalesced sum of cntsT row -> btot.
__global__ __launch_bounds__(256) void k_binB1(const int* __restrict__ cntsT,
                                               int* __restrict__ btot,
                                               int NB, int nblk) {
    int b = (blockIdx.x * 256 + threadIdx.x) >> 6;
    if (b >= NB) return;
    int lane = threadIdx.x & 63;
    const int* row = cntsT + (size_t)b * nblk;
    int s = 0;
    for (int k = lane; k < nblk; k += 64) s += row[k];
#pragma unroll
    for (int o = 32; o; o >>= 1) s += __shfl_xor(s, o);
    if (lane == 0) btot[b] = s;
}

// Single block: exclusive scan of bucket totals.
__global__ __launch_bounds__(1024) void k_binB2(const int* __restrict__ btot,
                                                int* __restrict__ bbase,
                                                int* __restrict__ bend,
                                                int* __restrict__ rp,
                                                int NB, int N, int Et) {
    __shared__ int lds[1024];
    int t = threadIdx.x;
    int v = (t < NB) ? btot[t] : 0;
    lds[t] = v; __syncthreads();
    int x = v;
    for (int o = 1; o < 1024; o <<= 1) {
        int y = (t >= o) ? lds[t - o] : 0;
        __syncthreads();
        x += y;
        lds[t] = x;
        __syncthreads();
    }
    if (t < NB) { bbase[t] = x - v; bend[t] = x; }
    if (t == 0) rp[N] = Et;
}

// One block per bucket: exclusive scan of its chunk counts + bbase -> gbaseT.
__global__ __launch_bounds__(256) void k_binB3(const int* __restrict__ cntsT,
                                               const int* __restrict__ bbase,
                                               int* __restrict__ gbaseT,
                                               int nblk) {
    __shared__ int lds[256];
    int b = blockIdx.x, t = threadIdx.x;
    const int* row = cntsT + (size_t)b * nblk;
    int* orow = gbaseT + (size_t)b * nblk;
    int carry = bbase[b];
    for (int base = 0; base < nblk; base += 256) {
        int k = base + t;
        int v = (k < nblk) ? row[k] : 0;
        lds[t] = v; __syncthreads();
        int x = v;
        for (int o = 1; o < 256; o <<= 1) {
            int y = (t >= o) ? lds[t - o] : 0;
            __syncthreads();
            x += y;
            lds[t] = x;
            __syncthreads();
        }
        if (k < nblk) orow[k] = carry + x - v;
        carry += lds[255];
        __syncthreads();
    }
}

__global__ __launch_bounds__(256) void k_binC(const int* __restrict__ srcs,
                                              const int* __restrict__ dsts,
                                              const int* __restrict__ gbaseT,
                                              unsigned* __restrict__ binned,
                                              int E, int Et, int NB, int nblk) {
    __shared__ int lcnt[NBMAX];
    int t = threadIdx.x;
    for (int i = t; i < NB; i += 256)
        lcnt[i] = gbaseT[(size_t)i * nblk + blockIdx.x];
    __syncthreads();
    int e0 = blockIdx.x * CHUNK;
#pragma unroll 4
    for (int it = 0; it < CHUNK / 256; ++it) {
        int e = e0 + it * 256 + t;
        if (e < Et) {
            int s, d;
            if (e < E) { s = srcs[e]; d = dsts[e]; } else { s = e - E; d = s; }
            int b = d >> BSH;
            int p = atomicAdd(&lcnt[b], 1);
            binned[p] = (unsigned)s | ((unsigned)(d & (BNODES - 1)) << 24);
        }
    }
}

__global__ __launch_bounds__(256) void k_binD(const unsigned* __restrict__ binned,
                                              const int* __restrict__ bbase,
                                              const int* __restrict__ bend,
                                              int* __restrict__ rp,
                                              int* __restrict__ csr, int N) {
    __shared__ int hist[BNODES];
    __shared__ int sc[256];
    __shared__ int lcnt[BNODES];
    int b = blockIdx.x, t = threadIdx.x;
    int base = bbase[b], end = bend[b];
    if (t < BNODES) hist[t] = 0;
    __syncthreads();
    for (int j = base + t; j < end; j += 256)
        atomicAdd(&hist[binned[j] >> 24], 1);
    __syncthreads();
    int v = (t < BNODES) ? hist[t] : 0;
    sc[t] = v; __syncthreads();
    int x = v;
    for (int o = 1; o < BNODES; o <<= 1) {
        int y = (t >= o) ? sc[t - o] : 0;
        __syncthreads();
        x += y;
        sc[t] = x;
        __syncthreads();
    }
    int pref = x - v;
    int g = (b << BSH) + t;
    if (t < BNODES && g < N) rp[g] = base + pref;
    if (t < BNODES) { sc[t] = pref; lcnt[t] = 0; }
    __syncthreads();
    for (int j = base + t; j < end; j += 256) {
        unsigned w = binned[j];
        int v2 = (int)(w >> 24);
        int s = (int)(w & 0xFFFFFFu);
        int p = atomicAdd(&lcnt[v2], 1);
        csr[base + sc[v2] + p] = s;
    }
}

// ---------------- GEMM1: h1 = fp16(x @ W1), fused fp32 alphas ----------------

__global__ __launch_bounds__(256) void k_gemm1(const float* __restrict__ x,
                                               const float* __restrict__ W,
                                               const float* __restrict__ avs,
                                               const float* __restrict__ avd,
                                               unsigned short* __restrict__ h,
                                               float* __restrict__ as,
                                               float* __restrict__ ad, int N) {
    __shared__ __align__(16) float Ws[F_IN * F_H];
    for (int i = threadIdx.x; i < F_IN * F_H; i += 256) Ws[i] = W[i];
    __syncthreads();
    int t = threadIdx.x;
    int r0 = blockIdx.x * 64 + (t >> 4) * 4;
    int c0 = (t & 15) * 4;
    if (r0 >= N) return;
    const float* xp = x + (size_t)r0 * F_IN;
    float acc[4][4] = {};
    for (int k4 = 0; k4 < F_IN / 4; ++k4) {
        int kb = k4 * 4;
        float4 w0 = *(const float4*)&Ws[(kb + 0) * F_H + c0];
        float4 w1 = *(const float4*)&Ws[(kb + 1) * F_H + c0];
        float4 w2 = *(const float4*)&Ws[(kb + 2) * F_H + c0];
        float4 w3 = *(const float4*)&Ws[(kb + 3) * F_H + c0];
#pragma unroll
        for (int r = 0; r < 4; ++r) {
            float4 xv = *(const float4*)&xp[(size_t)r * F_IN + kb];
            acc[r][0] += xv.x * w0.x + xv.y * w1.x + xv.z * w2.x + xv.w * w3.x;
            acc[r][1] += xv.x * w0.y + xv.y * w1.y + xv.z * w2.y + xv.w * w3.y;
            acc[r][2] += xv.x * w0.z + xv.y * w1.z + xv.z * w2.z + xv.w * w3.z;
            acc[r][3] += xv.x * w0.w + xv.y * w1.w + xv.z * w2.w + xv.w * w3.w;
        }
    }
    float4 avs4 = *(const float4*)&avs[c0];
    float4 avd4 = *(const float4*)&avd[c0];
#pragma unroll
    for (int r = 0; r < 4; ++r) {
        unsigned lo = (unsigned)f2h(acc[r][0]) | ((unsigned)f2h(acc[r][1]) << 16);
        unsigned hi = (unsigned)f2h(acc[r][2]) | ((unsigned)f2h(acc[r][3]) << 16);
        ((uint2*)h)[((size_t)(r0 + r) * F_H + c0) >> 2] = make_uint2(lo, hi);
        float ps = acc[r][0] * avs4.x + acc[r][1] * avs4.y + acc[r][2] * avs4.z + acc[r][3] * avs4.w;
        float pd = acc[r][0] * avd4.x + acc[r][1] * avd4.y + acc[r][2] * avd4.z + acc[r][3] * avd4.w;
#pragma unroll
        for (int o = 8; o; o >>= 1) {
            ps += __shfl_xor(ps, o, 16);
            pd += __shfl_xor(pd, o, 16);
        }
        if ((t & 15) == 0) { as[r0 + r] = ps; ad[r0 + r] = pd; }
    }
}

// ---------------- GEMM2: h2 = fp16(out1 @ W2) padded to 64 cols ----------------

__global__ __launch_bounds__(256) void k_gemm2(const float* __restrict__ xin,
                                               const float* __restrict__ W,
                                               const float* __restrict__ avs,
                                               const float* __restrict__ avd,
                                               unsigned short* __restrict__ h,
                                               float* __restrict__ as,
                                               float* __restrict__ ad, int N) {
    __shared__ __align__(16) float Ws[F_H * F_O];
    for (int i = threadIdx.x; i < F_H * F_O; i += 256) Ws[i] = W[i];
    __syncthreads();
    int t = threadIdx.x;
    int r0 = blockIdx.x * 64 + (t >> 3) * 2;
    int l = t & 7;
    if (r0 >= N) return;
    const float4* xa = (const float4*)(xin + (size_t)r0 * F_H);
    const float4* xb = (const float4*)(xin + (size_t)(r0 + 1) * F_H);
    float acca[5] = {}, accb[5] = {};
#pragma unroll
    for (int k4 = 0; k4 < F_H / 4; ++k4) {
        float4 xva = xa[k4];
        float4 xvb = xb[k4];
        int kb = k4 * 4;
#pragma unroll
        for (int kk = 0; kk < 4; ++kk) {
            const float* wr = &Ws[(kb + kk) * F_O + l];
            float w0 = wr[0], w1 = wr[8], w2 = wr[16], w3 = wr[24], w4 = wr[32];
            float xs = (&xva.x)[kk];
            acca[0] += xs * w0; acca[1] += xs * w1; acca[2] += xs * w2;
            acca[3] += xs * w3; acca[4] += xs * w4;
            float ys = (&xvb.x)[kk];
            accb[0] += ys * w0; accb[1] += ys * w1; accb[2] += ys * w2;
            accb[3] += ys * w3; accb[4] += ys * w4;
        }
    }
    float psa = 0.f, pda = 0.f, psb = 0.f, pdb = 0.f;
    unsigned short* ra = h + (size_t)r0 * F_H;     // padded row stride 64
    unsigned short* rb = h + (size_t)(r0 + 1) * F_H;
#pragma unroll
    for (int cc = 0; cc < 5; ++cc) {
        int c = l + 8 * cc;
        ra[c] = f2h(acca[cc]);
        rb[c] = f2h(accb[cc]);
        float vs = avs[c], vd = avd[c];
        psa += acca[cc] * vs; pda += acca[cc] * vd;
        psb += accb[cc] * vs; pdb += accb[cc] * vd;
    }
#pragma unroll
    for (int pp = 0; pp < 3; ++pp) {               // zero pad cols 40..63
        int c = 40 + l * 3 + pp;
        ra[c] = 0; rb[c] = 0;
    }
#pragma unroll
    for (int o = 4; o; o >>= 1) {
        psa += __shfl_xor(psa, o, 8);
        pda += __shfl_xor(pda, o, 8);
        psb += __shfl_xor(psb, o, 8);
        pdb += __shfl_xor(pdb, o, 8);
    }
    if (l == 0) { as[r0] = psa; ad[r0] = pda; as[r0 + 1] = psb; ad[r0 + 1] = pdb; }
}

// ---------------- Edge weights: w = exp(leaky(as[src]+ad[dst]) - 6) ----------

__global__ __launch_bounds__(256) void k_w(const int* __restrict__ rp,
                                           const int* __restrict__ csr,
                                           const float* __restrict__ as,
                                           const float* __restrict__ ad,
                                           uint2* __restrict__ ws, int N) {
    int i = (blockIdx.x * 256 + threadIdx.x) >> 6;
    if (i >= N) return;
    int lane = threadIdx.x & 63;
    int start = rp[i], end = rp[i + 1];
    float adi = ad[i];
    for (int j = start + lane; j < end; j += 64) {
        int s = csr[j];
        float e = as[s] + adi;
        e = (e > 0.f) ? e : 0.2f * e;
        ws[j] = make_uint2(__float_as_uint(__expf(e - 6.f)), (unsigned)s);
    }
}

// ---------------- Aggregation: one wave per dst node ----------------

template <int FOUT, bool RELU, bool LOGSM>
__global__ __launch_bounds__(256) void k_agg(const int* __restrict__ rp,
                                             const uint2* __restrict__ ws,
                                             const uint4* __restrict__ h4,
                                             const float* __restrict__ bias,
                                             float* __restrict__ out, int N) {
    int lane = threadIdx.x & 63;
    int i = (blockIdx.x * 256 + threadIdx.x) >> 6;
    if (i >= N) return;
    int start = rp[i], end = rp[i + 1];
    int grp = lane >> 3, c = lane & 7;
    int e1 = end - 1;
    __half2 a0[4] = {}, a1[4] = {};
    float sacc = 0.f;

    for (int jb = start; jb < end; jb += 32) {
        int j0 = jb + grp, j1 = jb + 8 + grp, j2 = jb + 16 + grp, j3 = jb + 24 + grp;
        uint2 t0 = ws[min(j0, e1)];
        uint2 t1 = ws[min(j1, e1)];
        uint2 t2 = ws[min(j2, e1)];
        uint2 t3 = ws[min(j3, e1)];
        uint4 h0 = h4[(size_t)t0.y * 8 + c];
        uint4 h1 = h4[(size_t)t1.y * 8 + c];
        uint4 h2 = h4[(size_t)t2.y * 8 + c];
        uint4 h3 = h4[(size_t)t3.y * 8 + c];
        float w0 = (j0 <= e1) ? __uint_as_float(t0.x) : 0.f;
        float w1 = (j1 <= e1) ? __uint_as_float(t1.x) : 0.f;
        float w2 = (j2 <= e1) ? __uint_as_float(t2.x) : 0.f;
        float w3 = (j3 <= e1) ? __uint_as_float(t3.x) : 0.f;
        sacc += (w0 + w1) + (w2 + w3);
        __half2 wh0 = __float2half2_rn(w0);
        __half2 wh1 = __float2half2_rn(w1);
        __half2 wh2 = __float2half2_rn(w2);
        __half2 wh3 = __float2half2_rn(w3);
        a0[0] = __hfma2(wh0, u2h(h0.x), a0[0]);
        a0[1] = __hfma2(wh0, u2h(h0.y), a0[1]);
        a0[2] = __hfma2(wh0, u2h(h0.z), a0[2]);
        a0[3] = __hfma2(wh0, u2h(h0.w), a0[3]);
        a1[0] = __hfma2(wh1, u2h(h1.x), a1[0]);
        a1[1] = __hfma2(wh1, u2h(h1.y), a1[1]);
        a1[2] = __hfma2(wh1, u2h(h1.z), a1[2]);
        a1[3] = __hfma2(wh1, u2h(h1.w), a1[3]);
        a0[0] = __hfma2(wh2, u2h(h2.x), a0[0]);
        a0[1] = __hfma2(wh2, u2h(h2.y), a0[1]);
        a0[2] = __hfma2(wh2, u2h(h2.z), a0[2]);
        a0[3] = __hfma2(wh2, u2h(h2.w), a0[3]);
        a1[0] = __hfma2(wh3, u2h(h3.x), a1[0]);
        a1[1] = __hfma2(wh3, u2h(h3.y), a1[1]);
        a1[2] = __hfma2(wh3, u2h(h3.z), a1[2]);
        a1[3] = __hfma2(wh3, u2h(h3.w), a1[3]);
    }
#pragma unroll
    for (int k = 0; k < 4; ++k) a0[k] = __hadd2(a0[k], a1[k]);
#pragma unroll
    for (int o = 8; o <= 32; o <<= 1) {
#pragma unroll
        for (int k = 0; k < 4; ++k) {
            unsigned u = __shfl_xor((int)h2u(a0[k]), o);
            a0[k] = __hadd2(a0[k], u2h((unsigned)u));
        }
        sacc += __shfl_xor(sacc, o);
    }
    float inv = 1.f / sacc;
    float f[8];
#pragma unroll
    for (int k = 0; k < 4; ++k) {
        float2 p = __half22float2(a0[k]);
        f[2 * k] = p.x; f[2 * k + 1] = p.y;
    }

    if (!LOGSM) {
        if (lane < 8) {
            float r[8];
#pragma unroll
            for (int k = 0; k < 8; ++k) {
                r[k] = f[k] * inv + bias[8 * lane + k];
                if (RELU) r[k] = fmaxf(r[k], 0.f);
            }
            float4* op = (float4*)(out + (size_t)i * FOUT + 8 * lane);
            op[0] = make_float4(r[0], r[1], r[2], r[3]);
            op[1] = make_float4(r[4], r[5], r[6], r[7]);
        }
    } else {
        constexpr int VC = FOUT / 8;         // valid chunks (5 for FOUT=40)
        bool act = (lane < VC);
        float v[8];
#pragma unroll
        for (int k = 0; k < 8; ++k)
            v[k] = act ? (f[k] * inv + bias[8 * lane + k]) : -INFINITY;
        float mx = v[0];
#pragma unroll
        for (int k = 1; k < 8; ++k) mx = fmaxf(mx, v[k]);
#pragma unroll
        for (int o = 1; o <= 4; o <<= 1) mx = fmaxf(mx, __shfl_xor(mx, o));
        float es = 0.f;
        if (act) {
#pragma unroll
            for (int k = 0; k < 8; ++k) es += __expf(v[k] - mx);
        }
#pragma unroll
        for (int o = 1; o <= 4; o <<= 1) es += __shfl_xor(es, o);
        if (act) {
            float lse = mx + __logf(es);
            float4* op = (float4*)(out + (size_t)i * FOUT + 8 * lane);
            op[0] = make_float4(v[0] - lse, v[1] - lse, v[2] - lse, v[3] - lse);
            op[1] = make_float4(v[4] - lse, v[5] - lse, v[6] - lse, v[7] - lse);
        }
    }
}

// ---------------- launch ----------------

extern "C" void kernel_launch(void* const* d_in, const int* in_sizes, int n_in,
                              void* d_out, int out_size, void* d_ws, size_t ws_size,
                              hipStream_t stream) {
    const float* x   = (const float*)d_in[0];
    const int* edges = (const int*)d_in[1];
    const float* W1  = (const float*)d_in[2];
    const float* av_s1 = (const float*)d_in[3];
    const float* av_d1 = (const float*)d_in[4];
    const float* b1  = (const float*)d_in[5];
    const float* W2  = (const float*)d_in[6];
    const float* av_s2 = (const float*)d_in[7];
    const float* av_d2 = (const float*)d_in[8];
    const float* b2  = (const float*)d_in[9];
    float* out = (float*)d_out;

    const int N  = in_sizes[0] / F_IN;
    const int E  = in_sizes[1] / 2;
    const int Et = E + N;
    const int NB = (N + BNODES - 1) >> BSH;
    const int nblkC = (Et + CHUNK - 1) / CHUNK;

    char* p = (char*)d_ws;
    auto alloc = [&](size_t bytes) {
        char* q = p;
        p += (bytes + 255) & ~(size_t)255;
        return (void*)q;
    };
    unsigned short* h1 = (unsigned short*)alloc((size_t)N * F_H * 2);  // fp16; reused as h2 (padded 64)
    float* out1   = (float*)alloc((size_t)N * F_H * 4);
    float* as1    = (float*)alloc((size_t)N * 4);
    float* ad1    = (float*)alloc((size_t)N * 4);
    float* as2    = (float*)alloc((size_t)N * 4);
    float* ad2    = (float*)alloc((size_t)N * 4);
    int* rp       = (int*)alloc((size_t)(N + 1) * 4);
    int* cntsT    = (int*)alloc((size_t)NBMAX * nblkC * 4);
    int* gbaseT   = (int*)alloc((size_t)NBMAX * nblkC * 4);
    int* btot     = (int*)alloc(NBMAX * 4);
    int* bbase    = (int*)alloc(NBMAX * 4);
    int* bend     = (int*)alloc(NBMAX * 4);
    unsigned* binned = (unsigned*)alloc((size_t)Et * 4);
    int* csr      = (int*)alloc((size_t)Et * 4);
    uint2* ws     = (uint2*)alloc((size_t)Et * 8);
    (void)n_in; (void)out_size; (void)ws_size;

    const int* srcs = edges;
    const int* dsts = edges + E;

    k_binA<<<nblkC, 256, 0, stream>>>(dsts, cntsT, E, Et, NB, nblkC);
    k_binB1<<<(NB + 3) / 4, 256, 0, stream>>>(cntsT, btot, NB, nblkC);
    k_binB2<<<1, 1024, 0, stream>>>(btot, bbase, bend, rp, NB, N, Et);
    k_binB3<<<NB, 256, 0, stream>>>(cntsT, bbase, gbaseT, nblkC);
    k_binC<<<nblkC, 256, 0, stream>>>(srcs, dsts, gbaseT, binned, E, Et, NB, nblkC);
    k_binD<<<NB, 256, 0, stream>>>(binned, bbase, bend, rp, csr, N);

    int gAgg = (N + 3) / 4;
    k_gemm1<<<(N + 63) / 64, 256, 0, stream>>>(x, W1, av_s1, av_d1, h1, as1, ad1, N);
    k_w<<<gAgg, 256, 0, stream>>>(rp, csr, as1, ad1, ws, N);
    k_agg<F_H, true, false><<<gAgg, 256, 0, stream>>>(rp, ws, (const uint4*)h1, b1, out1, N);
    k_gemm2<<<(N + 63) / 64, 256, 0, stream>>>(out1, W2, av_s2, av_d2, h1, as2, ad2, N);
    k_w<<<gAgg, 256, 0, stream>>>(rp, csr, as2, ad2, ws, N);
    k_agg<F_O, false, true><<<gAgg, 256, 0, stream>>>(rp, ws, (const uint4*)h1, b2, out, N);
}